// Round 3
// baseline (420.014 us; speedup 1.0000x reference)
//
#include <hip/hip_runtime.h>

// ChebConv K=6, sym norm, lambda_max=2 => L_hat = -D^{-1/2} A D^{-1/2}
// N=100000, E=1600000, F=64.
// R15: props split into two passes by SOURCE HALF (src<N/2 then src>=N/2).
// Each pass's gather footprint (3.2 MB fp8) fits the 4 MB per-XCD L2 ->
// gathers hit local L2 instead of thrashing to L3 (theory: MSHR x latency
// bound; R14's MLP null killed the concurrency theory). Pass A writes fp32
// partial rows (accP); pass B adds its half, applies the recurrence, writes
// bf16 + fp8. csr now stores A-edges first per node (bucketC builds midptr).
// mfma_out / radix build otherwise unchanged.

constexpr int F = 64;
constexpr int SCAN_ELEMS = 1024;
constexpr int BSH = 9;        // bucket shift: 512 nodes per bucket
constexpr int EPB = 2048;     // edges per partition block
constexpr int PNPW = 8;       // nodes per wave (prop kernels)

typedef __attribute__((ext_vector_type(8))) short short8;
typedef __attribute__((ext_vector_type(4))) float floatx4;
typedef __attribute__((ext_vector_type(2))) float floatx2;

#if defined(__has_builtin)
#if __has_builtin(__builtin_amdgcn_cvt_pk_f32_fp8) && __has_builtin(__builtin_amdgcn_cvt_pk_fp8_f32)
#define HAVE_FP8 1
#endif
#endif
#ifndef HAVE_FP8
#define HAVE_FP8 0
#endif

__device__ __forceinline__ unsigned short f_to_bf(float f) {
    unsigned u = __float_as_uint(f);
    u += 0x7FFFu + ((u >> 16) & 1u);  // RNE
    return (unsigned short)(u >> 16);
}
__device__ __forceinline__ float bf_to_f(unsigned short s) {
    return __uint_as_float(((unsigned)s) << 16);
}
__device__ __forceinline__ float4 bf4_to_f4(ushort4 u) {
    float4 f;
    f.x = bf_to_f(u.x); f.y = bf_to_f(u.y); f.z = bf_to_f(u.z); f.w = bf_to_f(u.w);
    return f;
}

#if HAVE_FP8
__device__ __forceinline__ float4 fp8x4_to_f4(unsigned u) {
    floatx2 lo = __builtin_amdgcn_cvt_pk_f32_fp8((int)u, false);
    floatx2 hi = __builtin_amdgcn_cvt_pk_f32_fp8((int)u, true);
    float4 f;
    f.x = lo.x; f.y = lo.y; f.z = hi.x; f.w = hi.y;
    return f;
}
__device__ __forceinline__ unsigned f4_to_fp8x4(float a, float b, float c, float d) {
    int pk = 0;
    pk = __builtin_amdgcn_cvt_pk_fp8_f32(a, b, pk, false);
    pk = __builtin_amdgcn_cvt_pk_fp8_f32(c, d, pk, true);
    return (unsigned)pk;
}
#else
__device__ __forceinline__ float4 fp8x4_to_f4(unsigned u) { return make_float4(0, 0, 0, 0); }
__device__ __forceinline__ unsigned f4_to_fp8x4(float a, float b, float c, float d) { return 0; }
#endif

// ---- fused dst/src bucket histograms ----
__global__ void hist2_kernel(const int* __restrict__ row, const int* __restrict__ col,
                             int* __restrict__ gcH, int* __restrict__ gcS,
                             int P, int G, int E) {
    __shared__ int hH[256], hS[256];
    const int tid = threadIdx.x, blk = blockIdx.x;
    hH[tid] = 0; hS[tid] = 0;
    __syncthreads();
    const int start = blk * EPB + tid * 8;
    if (start + 7 < E) {
        const int4 c0 = *(const int4*)(col + start);
        const int4 c1 = *(const int4*)(col + start + 4);
        const int4 r0 = *(const int4*)(row + start);
        const int4 r1 = *(const int4*)(row + start + 4);
        atomicAdd(&hH[c0.x >> BSH], 1); atomicAdd(&hH[c0.y >> BSH], 1);
        atomicAdd(&hH[c0.z >> BSH], 1); atomicAdd(&hH[c0.w >> BSH], 1);
        atomicAdd(&hH[c1.x >> BSH], 1); atomicAdd(&hH[c1.y >> BSH], 1);
        atomicAdd(&hH[c1.z >> BSH], 1); atomicAdd(&hH[c1.w >> BSH], 1);
        atomicAdd(&hS[r0.x >> BSH], 1); atomicAdd(&hS[r0.y >> BSH], 1);
        atomicAdd(&hS[r0.z >> BSH], 1); atomicAdd(&hS[r0.w >> BSH], 1);
        atomicAdd(&hS[r1.x >> BSH], 1); atomicAdd(&hS[r1.y >> BSH], 1);
        atomicAdd(&hS[r1.z >> BSH], 1); atomicAdd(&hS[r1.w >> BSH], 1);
    } else {
        for (int k = start; k < E && k < start + 8; ++k) {
            atomicAdd(&hH[col[k] >> BSH], 1);
            atomicAdd(&hS[row[k] >> BSH], 1);
        }
    }
    __syncthreads();
    if (tid < P) {
        gcH[(size_t)tid * G + blk] = hH[tid];
        gcS[(size_t)tid * G + blk] = hS[tid];
    }
}

__device__ __forceinline__ int4 load_cnt4(const int* __restrict__ cnt, int i, int N) {
    int4 v = make_int4(0, 0, 0, 0);
    if (i + 3 < N) {
        v = *(const int4*)(cnt + i);
    } else {
        if (i + 0 < N) v.x = cnt[i + 0];
        if (i + 1 < N) v.y = cnt[i + 1];
        if (i + 2 < N) v.z = cnt[i + 2];
        if (i + 3 < N) v.w = cnt[i + 3];
    }
    return v;
}

__global__ void scan1_kernel(const int* __restrict__ cnt, int* __restrict__ bsum, int N) {
    const int tid = threadIdx.x;
    const int i = blockIdx.x * SCAN_ELEMS + tid * 4;
    int4 v = load_cnt4(cnt, i, N);
    int s = v.x + v.y + v.z + v.w;
#pragma unroll
    for (int off = 1; off < 64; off <<= 1) s += __shfl_xor(s, off);
    __shared__ int ws[4];
    if ((tid & 63) == 0) ws[tid >> 6] = s;
    __syncthreads();
    if (tid == 0) bsum[blockIdx.x] = ws[0] + ws[1] + ws[2] + ws[3];
}

__global__ void scan2_kernel(const int* __restrict__ bsum, int* __restrict__ boff,
                             int* __restrict__ total_out, int nb) {
    const int tid = threadIdx.x;  // 256
    const int lane = tid & 63, w = tid >> 6;
    int v = (tid < nb) ? bsum[tid] : 0;
    int inc = v;
#pragma unroll
    for (int off = 1; off < 64; off <<= 1) {
        int t = __shfl_up(inc, off);
        if (lane >= off) inc += t;
    }
    __shared__ int wsum[4];
    if (lane == 63) wsum[w] = inc;
    __syncthreads();
    int wo = 0;
    for (int k = 0; k < w; ++k) wo += wsum[k];
    const int excl = wo + inc - v;
    if (tid < nb) boff[tid] = excl;
    if (tid == nb - 1) *total_out = excl + v;
}

__global__ void scan3_kernel(const int* __restrict__ cnt, const int* __restrict__ boff,
                             int* __restrict__ dst, int N) {
    const int tid = threadIdx.x;
    const int lane = tid & 63, w = tid >> 6;
    const int i = blockIdx.x * SCAN_ELEMS + tid * 4;
    int4 v = load_cnt4(cnt, i, N);
    const int s = v.x + v.y + v.z + v.w;
    int inc = s;
#pragma unroll
    for (int off = 1; off < 64; off <<= 1) {
        int t = __shfl_up(inc, off);
        if (lane >= off) inc += t;
    }
    __shared__ int wsum[4];
    if (lane == 63) wsum[w] = inc;
    __syncthreads();
    int wo = 0;
    for (int k = 0; k < w; ++k) wo += wsum[k];
    const int r0 = boff[blockIdx.x] + wo + inc - s;
    const int r1 = r0 + v.x, r2 = r1 + v.y, r3 = r2 + v.z;
    if (i + 3 < N) {
        *(int4*)(dst + i) = make_int4(r0, r1, r2, r3);
    } else {
        if (i + 0 < N) dst[i + 0] = r0;
        if (i + 1 < N) dst[i + 1] = r1;
        if (i + 2 < N) dst[i + 2] = r2;
        if (i + 3 < N) dst[i + 3] = r3;
    }
}

// fused scatter into dst-partitioned packed (dstlocal<<23|src) AND src-partitioned src list
__global__ void part2_kernel(const int* __restrict__ row, const int* __restrict__ col,
                             const int* __restrict__ goH, const int* __restrict__ goS,
                             int* __restrict__ partH, int* __restrict__ partS,
                             int P, int G, int E) {
    __shared__ int cH[256], cS[256];
    const int tid = threadIdx.x, blk = blockIdx.x;
    if (tid < P) {
        cH[tid] = goH[(size_t)tid * G + blk];
        cS[tid] = goS[(size_t)tid * G + blk];
    }
    __syncthreads();
    const int start = blk * EPB + tid * 8;
    for (int k = start; k < E && k < start + 8; ++k) {
        const int c = col[k], r = row[k];
        const int posH = atomicAdd(&cH[c >> BSH], 1);
        partH[posH] = ((c & ((1 << BSH) - 1)) << 23) | r;
        const int posS = atomicAdd(&cS[r >> BSH], 1);
        partS[posS] = r;
    }
}

// one block per bucket: exact per-node counts/ranks in LDS -> rowptr + midptr + csr
// csr stores per node: first the edges with src < H, then src >= H.
__global__ void bucketC_kernel(const int* __restrict__ part, const int* __restrict__ goff,
                               int* __restrict__ rowptr, int* __restrict__ midptr,
                               int* __restrict__ csr,
                               int P, int G, int N, int E, int H) {
    __shared__ int cnt[512];
    __shared__ int cntA[512];
    __shared__ int cursB[512];
    __shared__ int excl[512];
    __shared__ int wsum[4];
    const int tid = threadIdx.x;  // 256
    const int b = blockIdx.x;
    const int base_node = b << BSH;
    const int nn = min(512, N - base_node);
    const int estart = goff[(size_t)b * G];
    const int eend = (b + 1 < P) ? goff[(size_t)(b + 1) * G] : E;

    cnt[tid] = 0; cnt[tid + 256] = 0;
    cntA[tid] = 0; cntA[tid + 256] = 0;
    cursB[tid] = 0; cursB[tid + 256] = 0;
    __syncthreads();
    for (int i = estart + tid; i < eend; i += 256) {
        const int pk = part[i];
        const int ln = ((unsigned)pk) >> 23;
        atomicAdd(&cnt[ln], 1);
        if ((pk & 0x7FFFFF) < H) atomicAdd(&cntA[ln], 1);
    }
    __syncthreads();
    {
        const int lane = tid & 63, w = tid >> 6;
        const int a0 = cnt[2 * tid], a1 = cnt[2 * tid + 1];
        const int ps = a0 + a1;
        int inc = ps;
#pragma unroll
        for (int off = 1; off < 64; off <<= 1) {
            int t = __shfl_up(inc, off);
            if (lane >= off) inc += t;
        }
        if (lane == 63) wsum[w] = inc;
        __syncthreads();
        int wo = 0;
        for (int k = 0; k < w; ++k) wo += wsum[k];
        const int ep = wo + inc - ps;
        excl[2 * tid] = ep;
        excl[2 * tid + 1] = ep + a0;
    }
    __syncthreads();
    for (int ln = tid; ln < nn; ln += 256) {
        rowptr[base_node + ln] = estart + excl[ln];
        midptr[base_node + ln] = estart + excl[ln] + cntA[ln];
    }
    if (b == P - 1 && tid == 0) rowptr[N] = E;
    cnt[tid] = 0; cnt[tid + 256] = 0;  // cursor for A-edges
    __syncthreads();
    for (int i = estart + tid; i < eend; i += 256) {
        const int pk = part[i];
        const int ln = ((unsigned)pk) >> 23;
        const int r = pk & 0x7FFFFF;
        if (r < H) {
            const int pos = atomicAdd(&cnt[ln], 1);
            csr[estart + excl[ln] + pos] = r;
        } else {
            const int pos = atomicAdd(&cursB[ln], 1);
            csr[estart + excl[ln] + cntA[ln] + pos] = r;
        }
    }
}

// one block per src bucket: out-degree counts in LDS -> dinv/dinv2/rdinv
__global__ void bucketD_kernel(const int* __restrict__ partS, const int* __restrict__ goffS,
                               float* __restrict__ dinv, float* __restrict__ dinv2,
                               float* __restrict__ rdinv, int P, int G, int N, int E) {
    __shared__ int cnt[512];
    const int tid = threadIdx.x;  // 256
    const int b = blockIdx.x;
    const int base_node = b << BSH;
    const int nn = min(512, N - base_node);
    const int estart = goffS[(size_t)b * G];
    const int eend = (b + 1 < P) ? goffS[(size_t)(b + 1) * G] : E;
    cnt[tid] = 0; cnt[tid + 256] = 0;
    __syncthreads();
    for (int i = estart + tid; i < eend; i += 256)
        atomicAdd(&cnt[partS[i] - base_node], 1);
    __syncthreads();
    for (int l = tid; l < nn; l += 256) {
        const int dI = cnt[l];
        const float d = (float)dI;
        const bool ok = dI > 0;
        dinv[base_node + l]  = ok ? rsqrtf(d) : 0.0f;
        dinv2[base_node + l] = ok ? 1.0f / d : 0.0f;
        rdinv[base_node + l] = ok ? sqrtf(d) : 0.0f;
    }
}

// S0 = bf16(dinv (.) x) [+ fp8 copy], vectorized
__global__ void init_s0_kernel(const float* __restrict__ dinv, const float* __restrict__ x,
                               unsigned short* __restrict__ S0b, unsigned char* __restrict__ S0f8,
                               int NF, int write8) {
    int i = blockIdx.x * blockDim.x + threadIdx.x;
    int j = i * 4;
    if (j >= NF) return;
    const float dv = dinv[j >> 6];
    const float4 v = *(const float4*)(x + j);
    const float a = dv * v.x, bb = dv * v.y, c = dv * v.z, d = dv * v.w;
    ushort4 u;
    u.x = f_to_bf(a); u.y = f_to_bf(bb); u.z = f_to_bf(c); u.w = f_to_bf(d);
    *(ushort4*)(S0b + j) = u;
    if (write8) *(unsigned*)(S0f8 + j) = f4_to_fp8x4(a, bb, c, d);
}

// ---- two-pass props: pass A gathers src<H (L2-resident half), writes fp32
// partial; pass B gathers src>=H, adds partial, applies recurrence. ----

// Path B (bf16 gather) pass A
__global__ __launch_bounds__(256, 6)
void propA_g4(const int* __restrict__ rowptr, const int* __restrict__ midp,
              const int* __restrict__ csr, const unsigned short* __restrict__ Sprev,
              float* __restrict__ accP, int N) {
    const int lane = threadIdx.x & 63;
    const int g16 = lane & 48;
    const int fl = lane & 15;
    const int wave = threadIdx.x >> 6;
    const int wbase = (blockIdx.x * 4 + wave) * PNPW;
    for (int j = 0; j < PNPW; j += 4) {
        const int n = wbase + j + (g16 >> 4);
        const bool nv = n < N;
        const int nc = nv ? n : N - 1;
        const int s = rowptr[nc], e = midp[nc];
        const int len = e - s;
        float4 acc = {0.f, 0.f, 0.f, 0.f};
        for (int c = 0; c < len; c += 16) {
            const int ii = s + c + fl;
            const int idxv = csr[ii < e ? ii : e - 1];
            const int mm = min(16, len - c);
            ushort4 u[16];
#pragma unroll
            for (int t = 0; t < 16; ++t) {
                const int it = __shfl(idxv, g16 + t);
                u[t] = *(const ushort4*)(Sprev + (size_t)it * F + fl * 4);
            }
#pragma unroll
            for (int t = 0; t < 16; ++t) {
                if (t < mm) {
                    const float4 v = bf4_to_f4(u[t]);
                    acc.x += v.x; acc.y += v.y; acc.z += v.z; acc.w += v.w;
                }
            }
        }
        if (nv) *(float4*)(accP + (size_t)n * F + fl * 4) = acc;
    }
}

// Path B (bf16 gather) pass B
template <int FIRST>
__global__ __launch_bounds__(256, 6)
void propB_g4(const int* __restrict__ rowptr, const int* __restrict__ midp,
              const int* __restrict__ csr, const float* __restrict__ dinv2,
              const unsigned short* __restrict__ Sprev, const float* __restrict__ accP,
              const unsigned short* __restrict__ Sm2, unsigned short* __restrict__ Sk, int N) {
    const int lane = threadIdx.x & 63;
    const int g16 = lane & 48;
    const int fl = lane & 15;
    const int wave = threadIdx.x >> 6;
    const int wbase = (blockIdx.x * 4 + wave) * PNPW;
    for (int j = 0; j < PNPW; j += 4) {
        const int n = wbase + j + (g16 >> 4);
        const bool nv = n < N;
        const int nc = nv ? n : N - 1;
        const int s = midp[nc], e = rowptr[nc + 1];
        const int len = e - s;
        float4 acc = {0.f, 0.f, 0.f, 0.f};
        for (int c = 0; c < len; c += 16) {
            const int ii = s + c + fl;
            const int idxv = csr[ii < e ? ii : e - 1];
            const int mm = min(16, len - c);
            ushort4 u[16];
#pragma unroll
            for (int t = 0; t < 16; ++t) {
                const int it = __shfl(idxv, g16 + t);
                u[t] = *(const ushort4*)(Sprev + (size_t)it * F + fl * 4);
            }
#pragma unroll
            for (int t = 0; t < 16; ++t) {
                if (t < mm) {
                    const float4 v = bf4_to_f4(u[t]);
                    acc.x += v.x; acc.y += v.y; acc.z += v.z; acc.w += v.w;
                }
            }
        }
        if (nv) {
            const float4 pa = *(const float4*)(accP + (size_t)n * F + fl * 4);
            acc.x += pa.x; acc.y += pa.y; acc.z += pa.z; acc.w += pa.w;
            const float d2 = dinv2[n];
            float4 sn;
            if (FIRST) {
                sn.x = -d2 * acc.x; sn.y = -d2 * acc.y;
                sn.z = -d2 * acc.z; sn.w = -d2 * acc.w;
            } else {
                const float4 m2 = bf4_to_f4(*(const ushort4*)(Sm2 + (size_t)n * F + fl * 4));
                sn.x = -2.f * d2 * acc.x - m2.x; sn.y = -2.f * d2 * acc.y - m2.y;
                sn.z = -2.f * d2 * acc.z - m2.z; sn.w = -2.f * d2 * acc.w - m2.w;
            }
            ushort4 o;
            o.x = f_to_bf(sn.x); o.y = f_to_bf(sn.y);
            o.z = f_to_bf(sn.z); o.w = f_to_bf(sn.w);
            *(ushort4*)(Sk + (size_t)n * F + fl * 4) = o;
        }
    }
}

// Path A (fp8 gather) pass A
__global__ __launch_bounds__(256, 6)
void propA_f8(const int* __restrict__ rowptr, const int* __restrict__ midp,
              const int* __restrict__ csr, const unsigned char* __restrict__ S8prev,
              float* __restrict__ accP, int N) {
    const int lane = threadIdx.x & 63;
    const int g16 = lane & 48;
    const int fl = lane & 15;
    const int wave = threadIdx.x >> 6;
    const int wbase = (blockIdx.x * 4 + wave) * PNPW;
    for (int j = 0; j < PNPW; j += 4) {
        const int n = wbase + j + (g16 >> 4);
        const bool nv = n < N;
        const int nc = nv ? n : N - 1;
        const int s = rowptr[nc], e = midp[nc];
        const int len = e - s;
        float4 acc = {0.f, 0.f, 0.f, 0.f};
        for (int c = 0; c < len; c += 16) {
            const int ii = s + c + fl;
            const int idxv = csr[ii < e ? ii : e - 1];
            const int mm = min(16, len - c);
            unsigned u[16];
#pragma unroll
            for (int t = 0; t < 16; ++t) {
                const int it = __shfl(idxv, g16 + t);
                u[t] = *(const unsigned*)(S8prev + (size_t)it * F + fl * 4);
            }
#pragma unroll
            for (int t = 0; t < 16; ++t) {
                if (t < mm) {
                    const float4 v = fp8x4_to_f4(u[t]);
                    acc.x += v.x; acc.y += v.y; acc.z += v.z; acc.w += v.w;
                }
            }
        }
        if (nv) *(float4*)(accP + (size_t)n * F + fl * 4) = acc;
    }
}

// Path A (fp8 gather) pass B
template <int FIRST, int W8>
__global__ __launch_bounds__(256, 6)
void propB_f8(const int* __restrict__ rowptr, const int* __restrict__ midp,
              const int* __restrict__ csr, const float* __restrict__ dinv2,
              const unsigned char* __restrict__ S8prev, const float* __restrict__ accP,
              const unsigned short* __restrict__ Sm2, unsigned short* __restrict__ Sk,
              unsigned char* __restrict__ Sk8, int N) {
    const int lane = threadIdx.x & 63;
    const int g16 = lane & 48;
    const int fl = lane & 15;
    const int wave = threadIdx.x >> 6;
    const int wbase = (blockIdx.x * 4 + wave) * PNPW;
    for (int j = 0; j < PNPW; j += 4) {
        const int n = wbase + j + (g16 >> 4);
        const bool nv = n < N;
        const int nc = nv ? n : N - 1;
        const int s = midp[nc], e = rowptr[nc + 1];
        const int len = e - s;
        float4 acc = {0.f, 0.f, 0.f, 0.f};
        for (int c = 0; c < len; c += 16) {
            const int ii = s + c + fl;
            const int idxv = csr[ii < e ? ii : e - 1];
            const int mm = min(16, len - c);
            unsigned u[16];
#pragma unroll
            for (int t = 0; t < 16; ++t) {
                const int it = __shfl(idxv, g16 + t);
                u[t] = *(const unsigned*)(S8prev + (size_t)it * F + fl * 4);
            }
#pragma unroll
            for (int t = 0; t < 16; ++t) {
                if (t < mm) {
                    const float4 v = fp8x4_to_f4(u[t]);
                    acc.x += v.x; acc.y += v.y; acc.z += v.z; acc.w += v.w;
                }
            }
        }
        if (nv) {
            const float4 pa = *(const float4*)(accP + (size_t)n * F + fl * 4);
            acc.x += pa.x; acc.y += pa.y; acc.z += pa.z; acc.w += pa.w;
            const float d2 = dinv2[n];
            float4 sn;
            if (FIRST) {
                sn.x = -d2 * acc.x; sn.y = -d2 * acc.y;
                sn.z = -d2 * acc.z; sn.w = -d2 * acc.w;
            } else {
                const float4 m2 = bf4_to_f4(*(const ushort4*)(Sm2 + (size_t)n * F + fl * 4));
                sn.x = -2.f * d2 * acc.x - m2.x; sn.y = -2.f * d2 * acc.y - m2.y;
                sn.z = -2.f * d2 * acc.z - m2.z; sn.w = -2.f * d2 * acc.w - m2.w;
            }
            ushort4 o;
            o.x = f_to_bf(sn.x); o.y = f_to_bf(sn.y);
            o.z = f_to_bf(sn.z); o.w = f_to_bf(sn.w);
            *(ushort4*)(Sk + (size_t)n * F + fl * 4) = o;
            if (W8) *(unsigned*)(Sk8 + (size_t)n * F + fl * 4) = f4_to_fp8x4(sn.x, sn.y, sn.z, sn.w);
        }
    }
}

// Pre-swizzle bf16(W) into MFMA B-fragment order.
__global__ void wfrag_kernel(const float* __restrict__ W, unsigned short* __restrict__ Wfrag) {
    const int idx = blockIdx.x * blockDim.x + threadIdx.x;  // 3072 entries
    if (idx >= 4 * 12 * 64) return;
    const int lane = idx & 63;
    const int s = (idx >> 6) % 12;
    const int ft = idx / (64 * 12);
    const int n = ft * 16 + (lane & 15);
    const int quad = lane >> 4;
    unsigned short v[8];
#pragma unroll
    for (int j = 0; j < 8; ++j) {
        const int kg = s * 32 + quad * 8 + j;
        const int kk = kg >> 6, f = kg & 63;
        v[j] = f_to_bf(W[kk * F * F + f * F + n]);
    }
    ushort4 lo = {v[0], v[1], v[2], v[3]};
    ushort4 hi = {v[4], v[5], v[6], v[7]};
    *(ushort4*)(Wfrag + (size_t)idx * 8) = lo;
    *(ushort4*)(Wfrag + (size_t)idx * 8 + 4) = hi;
}

// out = relu(b + rdinv (.) sum_{k=0..5} Sk@Wk)   [x@W0 folded: x = rdinv*S0]
// deg-0 fixup: out = relu(b + x@(W0 - W2 + W4)).
// One WAVE per 16-row tile, all 4 feature tiles per wave (48 MFMAs).
__global__ __launch_bounds__(256, 3)
void mfma_out_kernel(const float* __restrict__ x, const unsigned short* __restrict__ Sstack,
                     const unsigned short* __restrict__ Wfrag, const float* __restrict__ rdinv,
                     const float* __restrict__ dinv2, const float* __restrict__ W,
                     const float* __restrict__ b, float* __restrict__ out, int N, int NF) {
    const int lane = threadIdx.x & 63;
    const int wave = threadIdx.x >> 6;      // row tile within block
    const int quad = lane >> 4;
    const int fl = lane & 15;
    const int tm = (blockIdx.x * 4 + wave) * 16;
    if (tm >= N) return;
    const int ma = tm + fl;
    const int mac = ma < N ? ma : N - 1;

    const unsigned short* sa = Sstack + (size_t)mac * F + quad * 8;

    // preload all 12 A fragments (independent HBM/L3 loads in flight)
    short8 Afr[12];
#pragma unroll
    for (int s = 0; s < 12; ++s) {
        const int kk = s >> 1, f0 = (s & 1) * 32;
        Afr[s] = *(const short8*)(sa + (size_t)kk * NF + f0);
    }

    floatx4 C0 = {0.f, 0.f, 0.f, 0.f};
    floatx4 C1 = {0.f, 0.f, 0.f, 0.f};
    floatx4 C2 = {0.f, 0.f, 0.f, 0.f};
    floatx4 C3 = {0.f, 0.f, 0.f, 0.f};
    const unsigned short* wf = Wfrag + (size_t)lane * 8;
#pragma unroll
    for (int s = 0; s < 12; ++s) {
        const short8 B0 = *(const short8*)(wf + (size_t)(0 * 12 + s) * 64 * 8);
        const short8 B1 = *(const short8*)(wf + (size_t)(1 * 12 + s) * 64 * 8);
        const short8 B2 = *(const short8*)(wf + (size_t)(2 * 12 + s) * 64 * 8);
        const short8 B3 = *(const short8*)(wf + (size_t)(3 * 12 + s) * 64 * 8);
        C0 = __builtin_amdgcn_mfma_f32_16x16x32_bf16(Afr[s], B0, C0, 0, 0, 0);
        C1 = __builtin_amdgcn_mfma_f32_16x16x32_bf16(Afr[s], B1, C1, 0, 0, 0);
        C2 = __builtin_amdgcn_mfma_f32_16x16x32_bf16(Afr[s], B2, C2, 0, 0, 0);
        C3 = __builtin_amdgcn_mfma_f32_16x16x32_bf16(Afr[s], B3, C3, 0, 0, 0);
    }

    // bias per feature tile (b is 256B, L1-hot)
    const float bl0 = b[0 * 16 + fl];
    const float bl1 = b[1 * 16 + fl];
    const float bl2 = b[2 * 16 + fl];
    const float bl3 = b[3 * 16 + fl];

#pragma unroll
    for (int r = 0; r < 4; ++r) {
        const int m = tm + quad * 4 + r;
        if (m >= N) continue;
        const float rs = rdinv[m];
        const bool z = (dinv2[m] == 0.0f);
        float v0 = rs * C0[r], v1 = rs * C1[r], v2 = rs * C2[r], v3 = rs * C3[r];
        if (z) {  // rare deg-0 rows: out = b + x@(W0 - W2 + W4)
            const float* xr = x + (size_t)m * F;
            float f0 = 0.f, f1 = 0.f, f2 = 0.f, f3 = 0.f;
            for (int f = 0; f < F; ++f) {
                const float xv = xr[f];
                const float* w0 = W + 0 * F * F + f * F;
                const float* w2 = W + 2 * F * F + f * F;
                const float* w4 = W + 4 * F * F + f * F;
                f0 += xv * (w0[0 * 16 + fl] - w2[0 * 16 + fl] + w4[0 * 16 + fl]);
                f1 += xv * (w0[1 * 16 + fl] - w2[1 * 16 + fl] + w4[1 * 16 + fl]);
                f2 += xv * (w0[2 * 16 + fl] - w2[2 * 16 + fl] + w4[2 * 16 + fl]);
                f3 += xv * (w0[3 * 16 + fl] - w2[3 * 16 + fl] + w4[3 * 16 + fl]);
            }
            v0 = f0; v1 = f1; v2 = f2; v3 = f3;
        }
        float* orow = out + (size_t)m * F;
        orow[0 * 16 + fl] = fmaxf(v0 + bl0, 0.f);
        orow[1 * 16 + fl] = fmaxf(v1 + bl1, 0.f);
        orow[2 * 16 + fl] = fmaxf(v2 + bl2, 0.f);
        orow[3 * 16 + fl] = fmaxf(v3 + bl3, 0.f);
    }
}

extern "C" void kernel_launch(void* const* d_in, const int* in_sizes, int n_in,
                              void* d_out, int out_size, void* d_ws, size_t ws_size,
                              hipStream_t stream) {
    const float* x = (const float*)d_in[0];
    const int* ei = (const int*)d_in[1];
    const float* W = (const float*)d_in[2];
    const float* b = (const float*)d_in[3];

    const int N = in_sizes[0] / F;
    const int E = in_sizes[1] / 2;
    const int NF = N * F;
    const int* row = ei;      // sources j
    const int* col = ei + E;  // targets i

    const int P = (N + 511) >> BSH;           // buckets (<=256 for N<=131072)
    const int G = (E + EPB - 1) / EPB;        // partition blocks
    const int M = P * G;                      // scan length
    const int H = N >> 1;                     // source-half split point

    // workspace allocator (64B-aligned chunks)
    char* p = (char*)d_ws;
    auto alloc = [&](size_t bytes) {
        char* r = p;
        p += (bytes + 63) & ~(size_t)63;
        return r;
    };
    float* dinv   = (float*)alloc((size_t)N * sizeof(float));
    float* dinv2  = (float*)alloc((size_t)N * sizeof(float));
    float* rdinv  = (float*)alloc((size_t)N * sizeof(float));
    int*   rowptr = (int*)alloc((size_t)(N + 1) * sizeof(int));
    int*   midptr = (int*)alloc((size_t)N * sizeof(int));
    int*   bsum   = (int*)alloc(256 * sizeof(int));
    int*   boff   = (int*)alloc(256 * sizeof(int));
    int*   totS   = (int*)alloc(64);
    int*   gcH    = (int*)alloc((size_t)M * sizeof(int));
    int*   goH    = (int*)alloc((size_t)M * sizeof(int));
    int*   gcS    = (int*)alloc((size_t)M * sizeof(int));
    int*   goS    = (int*)alloc((size_t)M * sizeof(int));
    int*   csr    = (int*)alloc((size_t)E * sizeof(int));
    unsigned short* Sstack = (unsigned short*)alloc((size_t)6 * NF * sizeof(unsigned short));
    unsigned short* Wfrag  = (unsigned short*)alloc((size_t)4 * 12 * 64 * 8 * sizeof(unsigned short));
    float* accP = (float*)alloc((size_t)NF * sizeof(float));   // fp32 pass-A partials
    unsigned char* F8A = (unsigned char*)alloc((size_t)NF);    // fp8 ping
    unsigned char* F8B = (unsigned char*)alloc((size_t)NF);    // fp8 pong
    const size_t needed = (size_t)(p - (char*)d_ws);
    const bool pathA = HAVE_FP8 && ws_size >= needed;
    // partH (E int, packed) aliases S0 (dead before init_s0); partS (E int) aliases S1+.
    int* partH = (int*)Sstack;
    int* partS = (int*)(Sstack + (size_t)NF);
    float* out = (float*)d_out;

    const int B = 256;
    const int nsbM = (M + SCAN_ELEMS - 1) / SCAN_ELEMS;  // <=256 required
    const int pgrid = (N + 4 * PNPW - 1) / (4 * PNPW);   // 4 waves/block

    hist2_kernel<<<G, B, 0, stream>>>(row, col, gcH, gcS, P, G, E);
    scan1_kernel<<<nsbM, B, 0, stream>>>(gcH, bsum, M);
    scan2_kernel<<<1, B, 0, stream>>>(bsum, boff, rowptr + N, nsbM);  // total == E
    scan3_kernel<<<nsbM, B, 0, stream>>>(gcH, boff, goH, M);
    scan1_kernel<<<nsbM, B, 0, stream>>>(gcS, bsum, M);
    scan2_kernel<<<1, B, 0, stream>>>(bsum, boff, totS, nsbM);
    scan3_kernel<<<nsbM, B, 0, stream>>>(gcS, boff, goS, M);
    part2_kernel<<<G, B, 0, stream>>>(row, col, goH, goS, partH, partS, P, G, E);
    bucketC_kernel<<<P, B, 0, stream>>>(partH, goH, rowptr, midptr, csr, P, G, N, E, H);
    bucketD_kernel<<<P, B, 0, stream>>>(partS, goS, dinv, dinv2, rdinv, P, G, N, E);

    wfrag_kernel<<<(4 * 12 * 64 + B - 1) / B, B, 0, stream>>>(W, Wfrag);
    init_s0_kernel<<<(NF / 4 + B - 1) / B, B, 0, stream>>>(dinv, x, Sstack, F8A, NF,
                                                           pathA ? 1 : 0);
    unsigned short* S1 = Sstack + (size_t)1 * NF;
    unsigned short* S2 = Sstack + (size_t)2 * NF;
    unsigned short* S3 = Sstack + (size_t)3 * NF;
    unsigned short* S4 = Sstack + (size_t)4 * NF;
    unsigned short* S5 = Sstack + (size_t)5 * NF;
    if (pathA) {
        propA_f8<<<pgrid, B, 0, stream>>>(rowptr, midptr, csr, F8A, accP, N);
        propB_f8<1, 1><<<pgrid, B, 0, stream>>>(rowptr, midptr, csr, dinv2, F8A, accP,
                                                Sstack, S1, F8B, N);
        propA_f8<<<pgrid, B, 0, stream>>>(rowptr, midptr, csr, F8B, accP, N);
        propB_f8<0, 1><<<pgrid, B, 0, stream>>>(rowptr, midptr, csr, dinv2, F8B, accP,
                                                Sstack, S2, F8A, N);
        propA_f8<<<pgrid, B, 0, stream>>>(rowptr, midptr, csr, F8A, accP, N);
        propB_f8<0, 1><<<pgrid, B, 0, stream>>>(rowptr, midptr, csr, dinv2, F8A, accP,
                                                S1, S3, F8B, N);
        propA_f8<<<pgrid, B, 0, stream>>>(rowptr, midptr, csr, F8B, accP, N);
        propB_f8<0, 1><<<pgrid, B, 0, stream>>>(rowptr, midptr, csr, dinv2, F8B, accP,
                                                S2, S4, F8A, N);
        propA_f8<<<pgrid, B, 0, stream>>>(rowptr, midptr, csr, F8A, accP, N);
        propB_f8<0, 0><<<pgrid, B, 0, stream>>>(rowptr, midptr, csr, dinv2, F8A, accP,
                                                S3, S5, F8B, N);
    } else {
        propA_g4<<<pgrid, B, 0, stream>>>(rowptr, midptr, csr, Sstack, accP, N);
        propB_g4<1><<<pgrid, B, 0, stream>>>(rowptr, midptr, csr, dinv2, Sstack, accP,
                                             Sstack, S1, N);
        propA_g4<<<pgrid, B, 0, stream>>>(rowptr, midptr, csr, S1, accP, N);
        propB_g4<0><<<pgrid, B, 0, stream>>>(rowptr, midptr, csr, dinv2, S1, accP,
                                             Sstack, S2, N);
        propA_g4<<<pgrid, B, 0, stream>>>(rowptr, midptr, csr, S2, accP, N);
        propB_g4<0><<<pgrid, B, 0, stream>>>(rowptr, midptr, csr, dinv2, S2, accP,
                                             S1, S3, N);
        propA_g4<<<pgrid, B, 0, stream>>>(rowptr, midptr, csr, S3, accP, N);
        propB_g4<0><<<pgrid, B, 0, stream>>>(rowptr, midptr, csr, dinv2, S3, accP,
                                             S2, S4, N);
        propA_g4<<<pgrid, B, 0, stream>>>(rowptr, midptr, csr, S4, accP, N);
        propB_g4<0><<<pgrid, B, 0, stream>>>(rowptr, midptr, csr, dinv2, S4, accP,
                                             S3, S5, N);
    }
    mfma_out_kernel<<<(N + 63) / 64, 256, 0, stream>>>(x, Sstack, Wfrag, rdinv, dinv2,
                                                       W, b, out, N, NF);
}

// Round 4
// 397.587 us; speedup vs baseline: 1.0564x; 1.0564x over previous
//
#include <hip/hip_runtime.h>

// ChebConv K=6, sym norm, lambda_max=2 => L_hat = -D^{-1/2} A D^{-1/2}
// N=100000, E=1600000, F=64.
// R16: revert R15 two-pass (regression: accP streaming polluted the L2 it was
// protecting). Back to R14 single-pass props + NON-TEMPORAL hints:
// nt-stores on Sk/Sk8/S0 outputs (next prop gathers hit clean L3, no peer-L2
// dirty snoops) and nt-loads on streaming inputs (csr, Sm2, dinv2, x) so L2
// capacity is reserved for the 6.4 MB fp8 gather footprint. Gather loads stay
// cached. mfma_out / radix build unchanged from R14.

constexpr int F = 64;
constexpr int SCAN_ELEMS = 1024;
constexpr int BSH = 9;        // bucket shift: 512 nodes per bucket
constexpr int EPB = 2048;     // edges per partition block
constexpr int PNPW = 8;       // nodes per wave (prop kernels)

typedef __attribute__((ext_vector_type(8))) short short8;
typedef __attribute__((ext_vector_type(4))) float floatx4;
typedef __attribute__((ext_vector_type(2))) float floatx2;
typedef __attribute__((ext_vector_type(4))) unsigned short u16x4;
typedef __attribute__((ext_vector_type(4))) float f32x4e;

#if defined(__has_builtin)
#if __has_builtin(__builtin_amdgcn_cvt_pk_f32_fp8) && __has_builtin(__builtin_amdgcn_cvt_pk_fp8_f32)
#define HAVE_FP8 1
#endif
#endif
#ifndef HAVE_FP8
#define HAVE_FP8 0
#endif

__device__ __forceinline__ unsigned short f_to_bf(float f) {
    unsigned u = __float_as_uint(f);
    u += 0x7FFFu + ((u >> 16) & 1u);  // RNE
    return (unsigned short)(u >> 16);
}
__device__ __forceinline__ float bf_to_f(unsigned short s) {
    return __uint_as_float(((unsigned)s) << 16);
}
__device__ __forceinline__ float4 bf4_to_f4(ushort4 u) {
    float4 f;
    f.x = bf_to_f(u.x); f.y = bf_to_f(u.y); f.z = bf_to_f(u.z); f.w = bf_to_f(u.w);
    return f;
}
__device__ __forceinline__ float4 bf4e_to_f4(u16x4 u) {
    float4 f;
    f.x = bf_to_f(u.x); f.y = bf_to_f(u.y); f.z = bf_to_f(u.z); f.w = bf_to_f(u.w);
    return f;
}

#if HAVE_FP8
__device__ __forceinline__ float4 fp8x4_to_f4(unsigned u) {
    floatx2 lo = __builtin_amdgcn_cvt_pk_f32_fp8((int)u, false);
    floatx2 hi = __builtin_amdgcn_cvt_pk_f32_fp8((int)u, true);
    float4 f;
    f.x = lo.x; f.y = lo.y; f.z = hi.x; f.w = hi.y;
    return f;
}
__device__ __forceinline__ unsigned f4_to_fp8x4(float a, float b, float c, float d) {
    int pk = 0;
    pk = __builtin_amdgcn_cvt_pk_fp8_f32(a, b, pk, false);
    pk = __builtin_amdgcn_cvt_pk_fp8_f32(c, d, pk, true);
    return (unsigned)pk;
}
#else
__device__ __forceinline__ float4 fp8x4_to_f4(unsigned u) { return make_float4(0, 0, 0, 0); }
__device__ __forceinline__ unsigned f4_to_fp8x4(float a, float b, float c, float d) { return 0; }
#endif

// ---- fused dst/src bucket histograms ----
__global__ void hist2_kernel(const int* __restrict__ row, const int* __restrict__ col,
                             int* __restrict__ gcH, int* __restrict__ gcS,
                             int P, int G, int E) {
    __shared__ int hH[256], hS[256];
    const int tid = threadIdx.x, blk = blockIdx.x;
    hH[tid] = 0; hS[tid] = 0;
    __syncthreads();
    const int start = blk * EPB + tid * 8;
    if (start + 7 < E) {
        const int4 c0 = *(const int4*)(col + start);
        const int4 c1 = *(const int4*)(col + start + 4);
        const int4 r0 = *(const int4*)(row + start);
        const int4 r1 = *(const int4*)(row + start + 4);
        atomicAdd(&hH[c0.x >> BSH], 1); atomicAdd(&hH[c0.y >> BSH], 1);
        atomicAdd(&hH[c0.z >> BSH], 1); atomicAdd(&hH[c0.w >> BSH], 1);
        atomicAdd(&hH[c1.x >> BSH], 1); atomicAdd(&hH[c1.y >> BSH], 1);
        atomicAdd(&hH[c1.z >> BSH], 1); atomicAdd(&hH[c1.w >> BSH], 1);
        atomicAdd(&hS[r0.x >> BSH], 1); atomicAdd(&hS[r0.y >> BSH], 1);
        atomicAdd(&hS[r0.z >> BSH], 1); atomicAdd(&hS[r0.w >> BSH], 1);
        atomicAdd(&hS[r1.x >> BSH], 1); atomicAdd(&hS[r1.y >> BSH], 1);
        atomicAdd(&hS[r1.z >> BSH], 1); atomicAdd(&hS[r1.w >> BSH], 1);
    } else {
        for (int k = start; k < E && k < start + 8; ++k) {
            atomicAdd(&hH[col[k] >> BSH], 1);
            atomicAdd(&hS[row[k] >> BSH], 1);
        }
    }
    __syncthreads();
    if (tid < P) {
        gcH[(size_t)tid * G + blk] = hH[tid];
        gcS[(size_t)tid * G + blk] = hS[tid];
    }
}

__device__ __forceinline__ int4 load_cnt4(const int* __restrict__ cnt, int i, int N) {
    int4 v = make_int4(0, 0, 0, 0);
    if (i + 3 < N) {
        v = *(const int4*)(cnt + i);
    } else {
        if (i + 0 < N) v.x = cnt[i + 0];
        if (i + 1 < N) v.y = cnt[i + 1];
        if (i + 2 < N) v.z = cnt[i + 2];
        if (i + 3 < N) v.w = cnt[i + 3];
    }
    return v;
}

__global__ void scan1_kernel(const int* __restrict__ cnt, int* __restrict__ bsum, int N) {
    const int tid = threadIdx.x;
    const int i = blockIdx.x * SCAN_ELEMS + tid * 4;
    int4 v = load_cnt4(cnt, i, N);
    int s = v.x + v.y + v.z + v.w;
#pragma unroll
    for (int off = 1; off < 64; off <<= 1) s += __shfl_xor(s, off);
    __shared__ int ws[4];
    if ((tid & 63) == 0) ws[tid >> 6] = s;
    __syncthreads();
    if (tid == 0) bsum[blockIdx.x] = ws[0] + ws[1] + ws[2] + ws[3];
}

__global__ void scan2_kernel(const int* __restrict__ bsum, int* __restrict__ boff,
                             int* __restrict__ total_out, int nb) {
    const int tid = threadIdx.x;  // 256
    const int lane = tid & 63, w = tid >> 6;
    int v = (tid < nb) ? bsum[tid] : 0;
    int inc = v;
#pragma unroll
    for (int off = 1; off < 64; off <<= 1) {
        int t = __shfl_up(inc, off);
        if (lane >= off) inc += t;
    }
    __shared__ int wsum[4];
    if (lane == 63) wsum[w] = inc;
    __syncthreads();
    int wo = 0;
    for (int k = 0; k < w; ++k) wo += wsum[k];
    const int excl = wo + inc - v;
    if (tid < nb) boff[tid] = excl;
    if (tid == nb - 1) *total_out = excl + v;
}

__global__ void scan3_kernel(const int* __restrict__ cnt, const int* __restrict__ boff,
                             int* __restrict__ dst, int N) {
    const int tid = threadIdx.x;
    const int lane = tid & 63, w = tid >> 6;
    const int i = blockIdx.x * SCAN_ELEMS + tid * 4;
    int4 v = load_cnt4(cnt, i, N);
    const int s = v.x + v.y + v.z + v.w;
    int inc = s;
#pragma unroll
    for (int off = 1; off < 64; off <<= 1) {
        int t = __shfl_up(inc, off);
        if (lane >= off) inc += t;
    }
    __shared__ int wsum[4];
    if (lane == 63) wsum[w] = inc;
    __syncthreads();
    int wo = 0;
    for (int k = 0; k < w; ++k) wo += wsum[k];
    const int r0 = boff[blockIdx.x] + wo + inc - s;
    const int r1 = r0 + v.x, r2 = r1 + v.y, r3 = r2 + v.z;
    if (i + 3 < N) {
        *(int4*)(dst + i) = make_int4(r0, r1, r2, r3);
    } else {
        if (i + 0 < N) dst[i + 0] = r0;
        if (i + 1 < N) dst[i + 1] = r1;
        if (i + 2 < N) dst[i + 2] = r2;
        if (i + 3 < N) dst[i + 3] = r3;
    }
}

// fused scatter into dst-partitioned packed (dstlocal<<23|src) AND src-partitioned src list
__global__ void part2_kernel(const int* __restrict__ row, const int* __restrict__ col,
                             const int* __restrict__ goH, const int* __restrict__ goS,
                             int* __restrict__ partH, int* __restrict__ partS,
                             int P, int G, int E) {
    __shared__ int cH[256], cS[256];
    const int tid = threadIdx.x, blk = blockIdx.x;
    if (tid < P) {
        cH[tid] = goH[(size_t)tid * G + blk];
        cS[tid] = goS[(size_t)tid * G + blk];
    }
    __syncthreads();
    const int start = blk * EPB + tid * 8;
    for (int k = start; k < E && k < start + 8; ++k) {
        const int c = col[k], r = row[k];
        const int posH = atomicAdd(&cH[c >> BSH], 1);
        partH[posH] = ((c & ((1 << BSH) - 1)) << 23) | r;
        const int posS = atomicAdd(&cS[r >> BSH], 1);
        partS[posS] = r;
    }
}

// one block per bucket: exact per-node counts/ranks in LDS -> rowptr + final csr
__global__ void bucketC_kernel(const int* __restrict__ part, const int* __restrict__ goff,
                               int* __restrict__ rowptr, int* __restrict__ csr,
                               int P, int G, int N, int E) {
    __shared__ int cnt[512];
    __shared__ int excl[512];
    __shared__ int wsum[4];
    const int tid = threadIdx.x;  // 256
    const int b = blockIdx.x;
    const int base_node = b << BSH;
    const int nn = min(512, N - base_node);
    const int estart = goff[(size_t)b * G];
    const int eend = (b + 1 < P) ? goff[(size_t)(b + 1) * G] : E;

    cnt[tid] = 0; cnt[tid + 256] = 0;
    __syncthreads();
    for (int i = estart + tid; i < eend; i += 256)
        atomicAdd(&cnt[((unsigned)part[i]) >> 23], 1);
    __syncthreads();
    {
        const int lane = tid & 63, w = tid >> 6;
        const int a0 = cnt[2 * tid], a1 = cnt[2 * tid + 1];
        const int ps = a0 + a1;
        int inc = ps;
#pragma unroll
        for (int off = 1; off < 64; off <<= 1) {
            int t = __shfl_up(inc, off);
            if (lane >= off) inc += t;
        }
        if (lane == 63) wsum[w] = inc;
        __syncthreads();
        int wo = 0;
        for (int k = 0; k < w; ++k) wo += wsum[k];
        const int ep = wo + inc - ps;
        excl[2 * tid] = ep;
        excl[2 * tid + 1] = ep + a0;
    }
    __syncthreads();
    if (tid < nn) rowptr[base_node + tid] = estart + excl[tid];
    for (int ln = 256 + tid; ln < nn; ln += 256) rowptr[base_node + ln] = estart + excl[ln];
    if (b == P - 1 && tid == 0) rowptr[N] = E;
    cnt[tid] = 0; cnt[tid + 256] = 0;
    __syncthreads();
    for (int i = estart + tid; i < eend; i += 256) {
        const int pk = part[i];
        const int ln = ((unsigned)pk) >> 23;
        const int pos = atomicAdd(&cnt[ln], 1);
        csr[estart + excl[ln] + pos] = pk & 0x7FFFFF;
    }
}

// one block per src bucket: out-degree counts in LDS -> dinv/dinv2/rdinv
__global__ void bucketD_kernel(const int* __restrict__ partS, const int* __restrict__ goffS,
                               float* __restrict__ dinv, float* __restrict__ dinv2,
                               float* __restrict__ rdinv, int P, int G, int N, int E) {
    __shared__ int cnt[512];
    const int tid = threadIdx.x;  // 256
    const int b = blockIdx.x;
    const int base_node = b << BSH;
    const int nn = min(512, N - base_node);
    const int estart = goffS[(size_t)b * G];
    const int eend = (b + 1 < P) ? goffS[(size_t)(b + 1) * G] : E;
    cnt[tid] = 0; cnt[tid + 256] = 0;
    __syncthreads();
    for (int i = estart + tid; i < eend; i += 256)
        atomicAdd(&cnt[partS[i] - base_node], 1);
    __syncthreads();
    for (int l = tid; l < nn; l += 256) {
        const int dI = cnt[l];
        const float d = (float)dI;
        const bool ok = dI > 0;
        dinv[base_node + l]  = ok ? rsqrtf(d) : 0.0f;
        dinv2[base_node + l] = ok ? 1.0f / d : 0.0f;
        rdinv[base_node + l] = ok ? sqrtf(d) : 0.0f;
    }
}

// S0 = bf16(dinv (.) x) [+ fp8 copy], vectorized; nt streaming
__global__ void init_s0_kernel(const float* __restrict__ dinv, const float* __restrict__ x,
                               unsigned short* __restrict__ S0b, unsigned char* __restrict__ S0f8,
                               int NF, int write8) {
    int i = blockIdx.x * blockDim.x + threadIdx.x;
    int j = i * 4;
    if (j >= NF) return;
    const float dv = dinv[j >> 6];
    const f32x4e v = __builtin_nontemporal_load((const f32x4e*)(x + j));
    const float a = dv * v.x, bb = dv * v.y, c = dv * v.z, d = dv * v.w;
    u16x4 u;
    u.x = f_to_bf(a); u.y = f_to_bf(bb); u.z = f_to_bf(c); u.w = f_to_bf(d);
    __builtin_nontemporal_store(u, (u16x4*)(S0b + j));
    if (write8) __builtin_nontemporal_store(f4_to_fp8x4(a, bb, c, d), (unsigned*)(S0f8 + j));
}

// ---- Path B prop: bf16 gather, 16-deep load batch, nt streaming ----
template <int FIRST>
__global__ __launch_bounds__(256, 6)
void prop_g4(const int* __restrict__ rowptr, const int* __restrict__ csr,
             const float* __restrict__ dinv2, const unsigned short* __restrict__ Sprev,
             const unsigned short* __restrict__ Sm2, unsigned short* __restrict__ Sk, int N) {
    const int lane = threadIdx.x & 63;
    const int g16 = lane & 48;
    const int fl = lane & 15;
    const int wave = threadIdx.x >> 6;
    const int wbase = (blockIdx.x * 4 + wave) * PNPW;
    for (int j = 0; j < PNPW; j += 4) {
        const int n = wbase + j + (g16 >> 4);
        const bool nv = n < N;
        const int nc = nv ? n : N - 1;
        const int s = rowptr[nc], e = rowptr[nc + 1];
        const int len = e - s;
        float4 acc = {0.f, 0.f, 0.f, 0.f};
        for (int c = 0; c < len; c += 16) {
            const int ii = s + c + fl;
            const int idxv = __builtin_nontemporal_load(csr + (ii < e ? ii : e - 1));
            const int mm = min(16, len - c);
            ushort4 u[16];
#pragma unroll
            for (int t = 0; t < 16; ++t) {
                const int it = __shfl(idxv, g16 + t);
                u[t] = *(const ushort4*)(Sprev + (size_t)it * F + fl * 4);
            }
#pragma unroll
            for (int t = 0; t < 16; ++t) {
                if (t < mm) {
                    const float4 v = bf4_to_f4(u[t]);
                    acc.x += v.x; acc.y += v.y; acc.z += v.z; acc.w += v.w;
                }
            }
        }
        if (nv) {
            const float d2 = __builtin_nontemporal_load(dinv2 + n);
            float4 sn;
            if (FIRST) {
                sn.x = -d2 * acc.x; sn.y = -d2 * acc.y;
                sn.z = -d2 * acc.z; sn.w = -d2 * acc.w;
            } else {
                const float4 m2 = bf4e_to_f4(
                    __builtin_nontemporal_load((const u16x4*)(Sm2 + (size_t)n * F + fl * 4)));
                sn.x = -2.f * d2 * acc.x - m2.x; sn.y = -2.f * d2 * acc.y - m2.y;
                sn.z = -2.f * d2 * acc.z - m2.z; sn.w = -2.f * d2 * acc.w - m2.w;
            }
            u16x4 o;
            o.x = f_to_bf(sn.x); o.y = f_to_bf(sn.y);
            o.z = f_to_bf(sn.z); o.w = f_to_bf(sn.w);
            __builtin_nontemporal_store(o, (u16x4*)(Sk + (size_t)n * F + fl * 4));
        }
    }
}

// ---- Path A prop: fp8 gather, 16-deep load batch, nt streaming ----
template <int FIRST, int W8>
__global__ __launch_bounds__(256, 6)
void prop_f8(const int* __restrict__ rowptr, const int* __restrict__ csr,
             const float* __restrict__ dinv2, const unsigned char* __restrict__ S8prev,
             const unsigned short* __restrict__ Sm2, unsigned short* __restrict__ Sk,
             unsigned char* __restrict__ Sk8, int N) {
    const int lane = threadIdx.x & 63;
    const int g16 = lane & 48;
    const int fl = lane & 15;
    const int wave = threadIdx.x >> 6;
    const int wbase = (blockIdx.x * 4 + wave) * PNPW;
    for (int j = 0; j < PNPW; j += 4) {
        const int n = wbase + j + (g16 >> 4);
        const bool nv = n < N;
        const int nc = nv ? n : N - 1;
        const int s = rowptr[nc], e = rowptr[nc + 1];
        const int len = e - s;
        float4 acc = {0.f, 0.f, 0.f, 0.f};
        for (int c = 0; c < len; c += 16) {
            const int ii = s + c + fl;
            const int idxv = __builtin_nontemporal_load(csr + (ii < e ? ii : e - 1));
            const int mm = min(16, len - c);
            unsigned u[16];
#pragma unroll
            for (int t = 0; t < 16; ++t) {
                const int it = __shfl(idxv, g16 + t);
                u[t] = *(const unsigned*)(S8prev + (size_t)it * F + fl * 4);
            }
#pragma unroll
            for (int t = 0; t < 16; ++t) {
                if (t < mm) {
                    const float4 v = fp8x4_to_f4(u[t]);
                    acc.x += v.x; acc.y += v.y; acc.z += v.z; acc.w += v.w;
                }
            }
        }
        if (nv) {
            const float d2 = __builtin_nontemporal_load(dinv2 + n);
            float4 sn;
            if (FIRST) {
                sn.x = -d2 * acc.x; sn.y = -d2 * acc.y;
                sn.z = -d2 * acc.z; sn.w = -d2 * acc.w;
            } else {
                const float4 m2 = bf4e_to_f4(
                    __builtin_nontemporal_load((const u16x4*)(Sm2 + (size_t)n * F + fl * 4)));
                sn.x = -2.f * d2 * acc.x - m2.x; sn.y = -2.f * d2 * acc.y - m2.y;
                sn.z = -2.f * d2 * acc.z - m2.z; sn.w = -2.f * d2 * acc.w - m2.w;
            }
            u16x4 o;
            o.x = f_to_bf(sn.x); o.y = f_to_bf(sn.y);
            o.z = f_to_bf(sn.z); o.w = f_to_bf(sn.w);
            __builtin_nontemporal_store(o, (u16x4*)(Sk + (size_t)n * F + fl * 4));
            if (W8) __builtin_nontemporal_store(f4_to_fp8x4(sn.x, sn.y, sn.z, sn.w),
                                                (unsigned*)(Sk8 + (size_t)n * F + fl * 4));
        }
    }
}

// Pre-swizzle bf16(W) into MFMA B-fragment order.
__global__ void wfrag_kernel(const float* __restrict__ W, unsigned short* __restrict__ Wfrag) {
    const int idx = blockIdx.x * blockDim.x + threadIdx.x;  // 3072 entries
    if (idx >= 4 * 12 * 64) return;
    const int lane = idx & 63;
    const int s = (idx >> 6) % 12;
    const int ft = idx / (64 * 12);
    const int n = ft * 16 + (lane & 15);
    const int quad = lane >> 4;
    unsigned short v[8];
#pragma unroll
    for (int j = 0; j < 8; ++j) {
        const int kg = s * 32 + quad * 8 + j;
        const int kk = kg >> 6, f = kg & 63;
        v[j] = f_to_bf(W[kk * F * F + f * F + n]);
    }
    ushort4 lo = {v[0], v[1], v[2], v[3]};
    ushort4 hi = {v[4], v[5], v[6], v[7]};
    *(ushort4*)(Wfrag + (size_t)idx * 8) = lo;
    *(ushort4*)(Wfrag + (size_t)idx * 8 + 4) = hi;
}

// out = relu(b + rdinv (.) sum_{k=0..5} Sk@Wk)   [x@W0 folded: x = rdinv*S0]
// deg-0 fixup: out = relu(b + x@(W0 - W2 + W4)).
// One WAVE per 16-row tile, all 4 feature tiles per wave (48 MFMAs).
__global__ __launch_bounds__(256, 3)
void mfma_out_kernel(const float* __restrict__ x, const unsigned short* __restrict__ Sstack,
                     const unsigned short* __restrict__ Wfrag, const float* __restrict__ rdinv,
                     const float* __restrict__ dinv2, const float* __restrict__ W,
                     const float* __restrict__ b, float* __restrict__ out, int N, int NF) {
    const int lane = threadIdx.x & 63;
    const int wave = threadIdx.x >> 6;      // row tile within block
    const int quad = lane >> 4;
    const int fl = lane & 15;
    const int tm = (blockIdx.x * 4 + wave) * 16;
    if (tm >= N) return;
    const int ma = tm + fl;
    const int mac = ma < N ? ma : N - 1;

    const unsigned short* sa = Sstack + (size_t)mac * F + quad * 8;

    // preload all 12 A fragments (independent HBM/L3 loads in flight)
    short8 Afr[12];
#pragma unroll
    for (int s = 0; s < 12; ++s) {
        const int kk = s >> 1, f0 = (s & 1) * 32;
        Afr[s] = *(const short8*)(sa + (size_t)kk * NF + f0);
    }

    floatx4 C0 = {0.f, 0.f, 0.f, 0.f};
    floatx4 C1 = {0.f, 0.f, 0.f, 0.f};
    floatx4 C2 = {0.f, 0.f, 0.f, 0.f};
    floatx4 C3 = {0.f, 0.f, 0.f, 0.f};
    const unsigned short* wf = Wfrag + (size_t)lane * 8;
#pragma unroll
    for (int s = 0; s < 12; ++s) {
        const short8 B0 = *(const short8*)(wf + (size_t)(0 * 12 + s) * 64 * 8);
        const short8 B1 = *(const short8*)(wf + (size_t)(1 * 12 + s) * 64 * 8);
        const short8 B2 = *(const short8*)(wf + (size_t)(2 * 12 + s) * 64 * 8);
        const short8 B3 = *(const short8*)(wf + (size_t)(3 * 12 + s) * 64 * 8);
        C0 = __builtin_amdgcn_mfma_f32_16x16x32_bf16(Afr[s], B0, C0, 0, 0, 0);
        C1 = __builtin_amdgcn_mfma_f32_16x16x32_bf16(Afr[s], B1, C1, 0, 0, 0);
        C2 = __builtin_amdgcn_mfma_f32_16x16x32_bf16(Afr[s], B2, C2, 0, 0, 0);
        C3 = __builtin_amdgcn_mfma_f32_16x16x32_bf16(Afr[s], B3, C3, 0, 0, 0);
    }

    // bias per feature tile (b is 256B, L1-hot)
    const float bl0 = b[0 * 16 + fl];
    const float bl1 = b[1 * 16 + fl];
    const float bl2 = b[2 * 16 + fl];
    const float bl3 = b[3 * 16 + fl];

#pragma unroll
    for (int r = 0; r < 4; ++r) {
        const int m = tm + quad * 4 + r;
        if (m >= N) continue;
        const float rs = rdinv[m];
        const bool z = (dinv2[m] == 0.0f);
        float v0 = rs * C0[r], v1 = rs * C1[r], v2 = rs * C2[r], v3 = rs * C3[r];
        if (z) {  // rare deg-0 rows: out = b + x@(W0 - W2 + W4)
            const float* xr = x + (size_t)m * F;
            float f0 = 0.f, f1 = 0.f, f2 = 0.f, f3 = 0.f;
            for (int f = 0; f < F; ++f) {
                const float xv = xr[f];
                const float* w0 = W + 0 * F * F + f * F;
                const float* w2 = W + 2 * F * F + f * F;
                const float* w4 = W + 4 * F * F + f * F;
                f0 += xv * (w0[0 * 16 + fl] - w2[0 * 16 + fl] + w4[0 * 16 + fl]);
                f1 += xv * (w0[1 * 16 + fl] - w2[1 * 16 + fl] + w4[1 * 16 + fl]);
                f2 += xv * (w0[2 * 16 + fl] - w2[2 * 16 + fl] + w4[2 * 16 + fl]);
                f3 += xv * (w0[3 * 16 + fl] - w2[3 * 16 + fl] + w4[3 * 16 + fl]);
            }
            v0 = f0; v1 = f1; v2 = f2; v3 = f3;
        }
        float* orow = out + (size_t)m * F;
        orow[0 * 16 + fl] = fmaxf(v0 + bl0, 0.f);
        orow[1 * 16 + fl] = fmaxf(v1 + bl1, 0.f);
        orow[2 * 16 + fl] = fmaxf(v2 + bl2, 0.f);
        orow[3 * 16 + fl] = fmaxf(v3 + bl3, 0.f);
    }
}

extern "C" void kernel_launch(void* const* d_in, const int* in_sizes, int n_in,
                              void* d_out, int out_size, void* d_ws, size_t ws_size,
                              hipStream_t stream) {
    const float* x = (const float*)d_in[0];
    const int* ei = (const int*)d_in[1];
    const float* W = (const float*)d_in[2];
    const float* b = (const float*)d_in[3];

    const int N = in_sizes[0] / F;
    const int E = in_sizes[1] / 2;
    const int NF = N * F;
    const int* row = ei;      // sources j
    const int* col = ei + E;  // targets i

    const int P = (N + 511) >> BSH;           // buckets (<=256 for N<=131072)
    const int G = (E + EPB - 1) / EPB;        // partition blocks
    const int M = P * G;                      // scan length

    // workspace allocator (64B-aligned chunks)
    char* p = (char*)d_ws;
    auto alloc = [&](size_t bytes) {
        char* r = p;
        p += (bytes + 63) & ~(size_t)63;
        return r;
    };
    float* dinv   = (float*)alloc((size_t)N * sizeof(float));
    float* dinv2  = (float*)alloc((size_t)N * sizeof(float));
    float* rdinv  = (float*)alloc((size_t)N * sizeof(float));
    int*   rowptr = (int*)alloc((size_t)(N + 1) * sizeof(int));
    int*   bsum   = (int*)alloc(256 * sizeof(int));
    int*   boff   = (int*)alloc(256 * sizeof(int));
    int*   totS   = (int*)alloc(64);
    int*   gcH    = (int*)alloc((size_t)M * sizeof(int));
    int*   goH    = (int*)alloc((size_t)M * sizeof(int));
    int*   gcS    = (int*)alloc((size_t)M * sizeof(int));
    int*   goS    = (int*)alloc((size_t)M * sizeof(int));
    int*   csr    = (int*)alloc((size_t)E * sizeof(int));
    unsigned short* Sstack = (unsigned short*)alloc((size_t)6 * NF * sizeof(unsigned short));
    unsigned short* Wfrag  = (unsigned short*)alloc((size_t)4 * 12 * 64 * 8 * sizeof(unsigned short));
    unsigned char* F8A = (unsigned char*)alloc((size_t)NF);   // fp8 ping
    unsigned char* F8B = (unsigned char*)alloc((size_t)NF);   // fp8 pong
    const size_t needed = (size_t)(p - (char*)d_ws);
    const bool pathA = HAVE_FP8 && ws_size >= needed;
    // partH (E int, packed) aliases S0 (dead before init_s0); partS (E int) aliases S1+.
    int* partH = (int*)Sstack;
    int* partS = (int*)(Sstack + (size_t)NF);
    float* out = (float*)d_out;

    const int B = 256;
    const int nsbM = (M + SCAN_ELEMS - 1) / SCAN_ELEMS;  // <=256 required
    const int pgrid = (N + 4 * PNPW - 1) / (4 * PNPW);   // 4 waves/block

    hist2_kernel<<<G, B, 0, stream>>>(row, col, gcH, gcS, P, G, E);
    scan1_kernel<<<nsbM, B, 0, stream>>>(gcH, bsum, M);
    scan2_kernel<<<1, B, 0, stream>>>(bsum, boff, rowptr + N, nsbM);  // total == E
    scan3_kernel<<<nsbM, B, 0, stream>>>(gcH, boff, goH, M);
    scan1_kernel<<<nsbM, B, 0, stream>>>(gcS, bsum, M);
    scan2_kernel<<<1, B, 0, stream>>>(bsum, boff, totS, nsbM);
    scan3_kernel<<<nsbM, B, 0, stream>>>(gcS, boff, goS, M);
    part2_kernel<<<G, B, 0, stream>>>(row, col, goH, goS, partH, partS, P, G, E);
    bucketC_kernel<<<P, B, 0, stream>>>(partH, goH, rowptr, csr, P, G, N, E);
    bucketD_kernel<<<P, B, 0, stream>>>(partS, goS, dinv, dinv2, rdinv, P, G, N, E);

    wfrag_kernel<<<(4 * 12 * 64 + B - 1) / B, B, 0, stream>>>(W, Wfrag);
    init_s0_kernel<<<(NF / 4 + B - 1) / B, B, 0, stream>>>(dinv, x, Sstack, F8A, NF,
                                                           pathA ? 1 : 0);
    unsigned short* S1 = Sstack + (size_t)1 * NF;
    unsigned short* S2 = Sstack + (size_t)2 * NF;
    unsigned short* S3 = Sstack + (size_t)3 * NF;
    unsigned short* S4 = Sstack + (size_t)4 * NF;
    unsigned short* S5 = Sstack + (size_t)5 * NF;
    if (pathA) {
        prop_f8<1, 1><<<pgrid, B, 0, stream>>>(rowptr, csr, dinv2, F8A, Sstack, S1, F8B, N);
        prop_f8<0, 1><<<pgrid, B, 0, stream>>>(rowptr, csr, dinv2, F8B, Sstack, S2, F8A, N);
        prop_f8<0, 1><<<pgrid, B, 0, stream>>>(rowptr, csr, dinv2, F8A, S1, S3, F8B, N);
        prop_f8<0, 1><<<pgrid, B, 0, stream>>>(rowptr, csr, dinv2, F8B, S2, S4, F8A, N);
        prop_f8<0, 0><<<pgrid, B, 0, stream>>>(rowptr, csr, dinv2, F8A, S3, S5, F8B, N);
    } else {
        prop_g4<1><<<pgrid, B, 0, stream>>>(rowptr, csr, dinv2, Sstack, Sstack, S1, N);
        prop_g4<0><<<pgrid, B, 0, stream>>>(rowptr, csr, dinv2, S1, Sstack, S2, N);
        prop_g4<0><<<pgrid, B, 0, stream>>>(rowptr, csr, dinv2, S2, S1, S3, N);
        prop_g4<0><<<pgrid, B, 0, stream>>>(rowptr, csr, dinv2, S3, S2, S4, N);
        prop_g4<0><<<pgrid, B, 0, stream>>>(rowptr, csr, dinv2, S4, S3, S5, N);
    }
    mfma_out_kernel<<<(N + 63) / 64, 256, 0, stream>>>(x, Sstack, Wfrag, rdinv, dinv2,
                                                       W, b, out, N, NF);
}

// Round 5
// 336.152 us; speedup vs baseline: 1.2495x; 1.1828x over previous
//
#include <hip/hip_runtime.h>

// ChebConv K=6, sym norm, lambda_max=2 => L_hat = -D^{-1/2} A D^{-1/2}
// N=100000, E=1600000, F=64.
// R17: (1) revert ALL nt hints in props/init_s0 (R16 measured regressor:
// nt-stores evicted next prop's gather rows from L2; nt csr loads uncached
// csr). (2) merged scan chains: gc = [gcH|gcS] contiguous, one scan1/2/3 at
// SCAN_ELEMS=2048 (goS biased +E, subtracted at use). (3) bucketC+bucketD
// merged into one 2P-block dispatch. (4) wfrag+init_s0 merged; part2 loads
// vectorized. (5) mfma_out: nt-loads on single-use Sstack reads, nt-stores
// on out. fp8 path deleted (never active: prop_g4 in top-5 proved fallback).

constexpr int F = 64;
constexpr int SCAN_ELEMS = 2048;  // 256 threads x 8
constexpr int BSH = 9;            // bucket shift: 512 nodes per bucket
constexpr int EPB = 2048;         // edges per partition block
constexpr int PNPW = 8;           // nodes per wave (prop kernels)
constexpr int WFRAG_BLOCKS = 12;  // 4*12*64 / 256

typedef __attribute__((ext_vector_type(8))) short short8;
typedef __attribute__((ext_vector_type(4))) float floatx4;

__device__ __forceinline__ unsigned short f_to_bf(float f) {
    unsigned u = __float_as_uint(f);
    u += 0x7FFFu + ((u >> 16) & 1u);  // RNE
    return (unsigned short)(u >> 16);
}
__device__ __forceinline__ float bf_to_f(unsigned short s) {
    return __uint_as_float(((unsigned)s) << 16);
}
__device__ __forceinline__ float4 bf4_to_f4(ushort4 u) {
    float4 f;
    f.x = bf_to_f(u.x); f.y = bf_to_f(u.y); f.z = bf_to_f(u.z); f.w = bf_to_f(u.w);
    return f;
}

// ---- fused dst/src bucket histograms ----
__global__ void hist2_kernel(const int* __restrict__ row, const int* __restrict__ col,
                             int* __restrict__ gcH, int* __restrict__ gcS,
                             int P, int G, int E) {
    __shared__ int hH[256], hS[256];
    const int tid = threadIdx.x, blk = blockIdx.x;
    hH[tid] = 0; hS[tid] = 0;
    __syncthreads();
    const int start = blk * EPB + tid * 8;
    if (start + 7 < E) {
        const int4 c0 = *(const int4*)(col + start);
        const int4 c1 = *(const int4*)(col + start + 4);
        const int4 r0 = *(const int4*)(row + start);
        const int4 r1 = *(const int4*)(row + start + 4);
        atomicAdd(&hH[c0.x >> BSH], 1); atomicAdd(&hH[c0.y >> BSH], 1);
        atomicAdd(&hH[c0.z >> BSH], 1); atomicAdd(&hH[c0.w >> BSH], 1);
        atomicAdd(&hH[c1.x >> BSH], 1); atomicAdd(&hH[c1.y >> BSH], 1);
        atomicAdd(&hH[c1.z >> BSH], 1); atomicAdd(&hH[c1.w >> BSH], 1);
        atomicAdd(&hS[r0.x >> BSH], 1); atomicAdd(&hS[r0.y >> BSH], 1);
        atomicAdd(&hS[r0.z >> BSH], 1); atomicAdd(&hS[r0.w >> BSH], 1);
        atomicAdd(&hS[r1.x >> BSH], 1); atomicAdd(&hS[r1.y >> BSH], 1);
        atomicAdd(&hS[r1.z >> BSH], 1); atomicAdd(&hS[r1.w >> BSH], 1);
    } else {
        for (int k = start; k < E && k < start + 8; ++k) {
            atomicAdd(&hH[col[k] >> BSH], 1);
            atomicAdd(&hS[row[k] >> BSH], 1);
        }
    }
    __syncthreads();
    if (tid < P) {
        gcH[(size_t)tid * G + blk] = hH[tid];
        gcS[(size_t)tid * G + blk] = hS[tid];
    }
}

__device__ __forceinline__ int4 load_cnt4(const int* __restrict__ cnt, int i, int N) {
    int4 v = make_int4(0, 0, 0, 0);
    if (i + 3 < N) {
        v = *(const int4*)(cnt + i);
    } else {
        if (i + 0 < N) v.x = cnt[i + 0];
        if (i + 1 < N) v.y = cnt[i + 1];
        if (i + 2 < N) v.z = cnt[i + 2];
        if (i + 3 < N) v.w = cnt[i + 3];
    }
    return v;
}

__global__ void scan1_kernel(const int* __restrict__ cnt, int* __restrict__ bsum, int N) {
    const int tid = threadIdx.x;
    const int i = blockIdx.x * SCAN_ELEMS + tid * 8;
    int4 va = load_cnt4(cnt, i, N);
    int4 vb = load_cnt4(cnt, i + 4, N);
    int s = va.x + va.y + va.z + va.w + vb.x + vb.y + vb.z + vb.w;
#pragma unroll
    for (int off = 1; off < 64; off <<= 1) s += __shfl_xor(s, off);
    __shared__ int ws[4];
    if ((tid & 63) == 0) ws[tid >> 6] = s;
    __syncthreads();
    if (tid == 0) bsum[blockIdx.x] = ws[0] + ws[1] + ws[2] + ws[3];
}

__global__ void scan2_kernel(const int* __restrict__ bsum, int* __restrict__ boff,
                             int* __restrict__ total_out, int nb) {
    const int tid = threadIdx.x;  // 256
    const int lane = tid & 63, w = tid >> 6;
    int v = (tid < nb) ? bsum[tid] : 0;
    int inc = v;
#pragma unroll
    for (int off = 1; off < 64; off <<= 1) {
        int t = __shfl_up(inc, off);
        if (lane >= off) inc += t;
    }
    __shared__ int wsum[4];
    if (lane == 63) wsum[w] = inc;
    __syncthreads();
    int wo = 0;
    for (int k = 0; k < w; ++k) wo += wsum[k];
    const int excl = wo + inc - v;
    if (tid < nb) boff[tid] = excl;
    if (tid == nb - 1) *total_out = excl + v;
}

__global__ void scan3_kernel(const int* __restrict__ cnt, const int* __restrict__ boff,
                             int* __restrict__ dst, int N) {
    const int tid = threadIdx.x;
    const int lane = tid & 63, w = tid >> 6;
    const int i = blockIdx.x * SCAN_ELEMS + tid * 8;
    int4 va = load_cnt4(cnt, i, N);
    int4 vb = load_cnt4(cnt, i + 4, N);
    const int s = va.x + va.y + va.z + va.w + vb.x + vb.y + vb.z + vb.w;
    int inc = s;
#pragma unroll
    for (int off = 1; off < 64; off <<= 1) {
        int t = __shfl_up(inc, off);
        if (lane >= off) inc += t;
    }
    __shared__ int wsum[4];
    if (lane == 63) wsum[w] = inc;
    __syncthreads();
    int wo = 0;
    for (int k = 0; k < w; ++k) wo += wsum[k];
    const int r0 = boff[blockIdx.x] + wo + inc - s;
    const int r1 = r0 + va.x, r2 = r1 + va.y, r3 = r2 + va.z;
    const int r4 = r3 + va.w, r5 = r4 + vb.x, r6 = r5 + vb.y, r7 = r6 + vb.z;
    if (i + 3 < N) {
        *(int4*)(dst + i) = make_int4(r0, r1, r2, r3);
    } else {
        if (i + 0 < N) dst[i + 0] = r0;
        if (i + 1 < N) dst[i + 1] = r1;
        if (i + 2 < N) dst[i + 2] = r2;
    }
    if (i + 7 < N) {
        *(int4*)(dst + i + 4) = make_int4(r4, r5, r6, r7);
    } else {
        if (i + 4 < N) dst[i + 4] = r4;
        if (i + 5 < N) dst[i + 5] = r5;
        if (i + 6 < N) dst[i + 6] = r6;
    }
}

// fused scatter into dst-partitioned packed (dstlocal<<23|src) AND src-partitioned src list
// goS entries carry a +E bias (merged scan); subtracted at LDS init.
__global__ void part2_kernel(const int* __restrict__ row, const int* __restrict__ col,
                             const int* __restrict__ goH, const int* __restrict__ goS,
                             int* __restrict__ partH, int* __restrict__ partS,
                             int P, int G, int E) {
    __shared__ int cH[256], cS[256];
    const int tid = threadIdx.x, blk = blockIdx.x;
    if (tid < P) {
        cH[tid] = goH[(size_t)tid * G + blk];
        cS[tid] = goS[(size_t)tid * G + blk] - E;
    }
    __syncthreads();
    const int start = blk * EPB + tid * 8;
    if (start + 7 < E) {
        const int4 c0 = *(const int4*)(col + start);
        const int4 c1 = *(const int4*)(col + start + 4);
        const int4 r0 = *(const int4*)(row + start);
        const int4 r1 = *(const int4*)(row + start + 4);
#define P2_DO(c, r)                                              \
        {                                                        \
            const int posH = atomicAdd(&cH[(c) >> BSH], 1);      \
            partH[posH] = (((c) & ((1 << BSH) - 1)) << 23) | (r);\
            const int posS = atomicAdd(&cS[(r) >> BSH], 1);      \
            partS[posS] = (r);                                   \
        }
        P2_DO(c0.x, r0.x) P2_DO(c0.y, r0.y) P2_DO(c0.z, r0.z) P2_DO(c0.w, r0.w)
        P2_DO(c1.x, r1.x) P2_DO(c1.y, r1.y) P2_DO(c1.z, r1.z) P2_DO(c1.w, r1.w)
#undef P2_DO
    } else {
        for (int k = start; k < E && k < start + 8; ++k) {
            const int c = col[k], r = row[k];
            const int posH = atomicAdd(&cH[c >> BSH], 1);
            partH[posH] = ((c & ((1 << BSH) - 1)) << 23) | r;
            const int posS = atomicAdd(&cS[r >> BSH], 1);
            partS[posS] = r;
        }
    }
}

// merged bucketC (blocks [0,P)) + bucketD (blocks [P,2P)).
// goffS entries carry +E bias (merged scan) -> subtract.
__global__ void bucketCD_kernel(const int* __restrict__ part, const int* __restrict__ goff,
                                const int* __restrict__ partS, const int* __restrict__ goffS,
                                int* __restrict__ rowptr, int* __restrict__ csr,
                                float* __restrict__ dinv, float* __restrict__ dinv2,
                                float* __restrict__ rdinv,
                                int P, int G, int N, int E) {
    __shared__ int cnt[512];
    __shared__ int excl[512];
    __shared__ int wsum[4];
    const int tid = threadIdx.x;  // 256
    const int bb = blockIdx.x;
    if (bb < P) {
        // ---- bucketC: rowptr + csr ----
        const int b = bb;
        const int base_node = b << BSH;
        const int nn = min(512, N - base_node);
        const int estart = goff[(size_t)b * G];
        const int eend = (b + 1 < P) ? goff[(size_t)(b + 1) * G] : E;

        cnt[tid] = 0; cnt[tid + 256] = 0;
        __syncthreads();
        for (int i = estart + tid; i < eend; i += 256)
            atomicAdd(&cnt[((unsigned)part[i]) >> 23], 1);
        __syncthreads();
        {
            const int lane = tid & 63, w = tid >> 6;
            const int a0 = cnt[2 * tid], a1 = cnt[2 * tid + 1];
            const int ps = a0 + a1;
            int inc = ps;
#pragma unroll
            for (int off = 1; off < 64; off <<= 1) {
                int t = __shfl_up(inc, off);
                if (lane >= off) inc += t;
            }
            if (lane == 63) wsum[w] = inc;
            __syncthreads();
            int wo = 0;
            for (int k = 0; k < w; ++k) wo += wsum[k];
            const int ep = wo + inc - ps;
            excl[2 * tid] = ep;
            excl[2 * tid + 1] = ep + a0;
        }
        __syncthreads();
        for (int ln = tid; ln < nn; ln += 256) rowptr[base_node + ln] = estart + excl[ln];
        if (b == P - 1 && tid == 0) rowptr[N] = E;
        cnt[tid] = 0; cnt[tid + 256] = 0;
        __syncthreads();
        for (int i = estart + tid; i < eend; i += 256) {
            const int pk = part[i];
            const int ln = ((unsigned)pk) >> 23;
            const int pos = atomicAdd(&cnt[ln], 1);
            csr[estart + excl[ln] + pos] = pk & 0x7FFFFF;
        }
    } else {
        // ---- bucketD: out-degrees -> dinv/dinv2/rdinv ----
        const int b = bb - P;
        const int base_node = b << BSH;
        const int nn = min(512, N - base_node);
        const int estart = goffS[(size_t)b * G] - E;
        const int eend = ((b + 1 < P) ? goffS[(size_t)(b + 1) * G] - E : E);
        cnt[tid] = 0; cnt[tid + 256] = 0;
        __syncthreads();
        for (int i = estart + tid; i < eend; i += 256)
            atomicAdd(&cnt[partS[i] - base_node], 1);
        __syncthreads();
        for (int l = tid; l < nn; l += 256) {
            const int dI = cnt[l];
            const float d = (float)dI;
            const bool ok = dI > 0;
            dinv[base_node + l]  = ok ? rsqrtf(d) : 0.0f;
            dinv2[base_node + l] = ok ? 1.0f / d : 0.0f;
            rdinv[base_node + l] = ok ? sqrtf(d) : 0.0f;
        }
    }
}

// merged: blocks [0,WFRAG_BLOCKS) pre-swizzle bf16(W) into MFMA B-fragment
// order; remaining blocks compute S0 = bf16(dinv (.) x).
__global__ void init_ws0_kernel(const float* __restrict__ W, unsigned short* __restrict__ Wfrag,
                                const float* __restrict__ dinv, const float* __restrict__ x,
                                unsigned short* __restrict__ S0b, int NF) {
    const int tid = threadIdx.x;
    const int bid = blockIdx.x;
    if (bid < WFRAG_BLOCKS) {
        const int idx = bid * 256 + tid;  // 3072 entries
        if (idx >= 4 * 12 * 64) return;
        const int lane = idx & 63;
        const int s = (idx >> 6) % 12;
        const int ft = idx / (64 * 12);
        const int n = ft * 16 + (lane & 15);
        const int quad = lane >> 4;
        unsigned short v[8];
#pragma unroll
        for (int j = 0; j < 8; ++j) {
            const int kg = s * 32 + quad * 8 + j;
            const int kk = kg >> 6, f = kg & 63;
            v[j] = f_to_bf(W[kk * F * F + f * F + n]);
        }
        ushort4 lo = {v[0], v[1], v[2], v[3]};
        ushort4 hi = {v[4], v[5], v[6], v[7]};
        *(ushort4*)(Wfrag + (size_t)idx * 8) = lo;
        *(ushort4*)(Wfrag + (size_t)idx * 8 + 4) = hi;
    } else {
        const int i = (bid - WFRAG_BLOCKS) * 256 + tid;
        const int j = i * 4;
        if (j >= NF) return;
        const float dv = dinv[j >> 6];
        const float4 v = *(const float4*)(x + j);
        ushort4 u;
        u.x = f_to_bf(dv * v.x); u.y = f_to_bf(dv * v.y);
        u.z = f_to_bf(dv * v.z); u.w = f_to_bf(dv * v.w);
        *(ushort4*)(S0b + j) = u;
    }
}

// ---- prop: bf16 gather, 16-deep load batch (no nt hints) ----
template <int FIRST>
__global__ __launch_bounds__(256, 6)
void prop_g4(const int* __restrict__ rowptr, const int* __restrict__ csr,
             const float* __restrict__ dinv2, const unsigned short* __restrict__ Sprev,
             const unsigned short* __restrict__ Sm2, unsigned short* __restrict__ Sk, int N) {
    const int lane = threadIdx.x & 63;
    const int g16 = lane & 48;
    const int fl = lane & 15;
    const int wave = threadIdx.x >> 6;
    const int wbase = (blockIdx.x * 4 + wave) * PNPW;
    for (int j = 0; j < PNPW; j += 4) {
        const int n = wbase + j + (g16 >> 4);
        const bool nv = n < N;
        const int nc = nv ? n : N - 1;
        const int s = rowptr[nc], e = rowptr[nc + 1];
        const int len = e - s;
        float4 acc = {0.f, 0.f, 0.f, 0.f};
        for (int c = 0; c < len; c += 16) {
            const int ii = s + c + fl;
            const int idxv = csr[ii < e ? ii : e - 1];
            const int mm = min(16, len - c);
            ushort4 u[16];
#pragma unroll
            for (int t = 0; t < 16; ++t) {
                const int it = __shfl(idxv, g16 + t);
                u[t] = *(const ushort4*)(Sprev + (size_t)it * F + fl * 4);
            }
#pragma unroll
            for (int t = 0; t < 16; ++t) {
                if (t < mm) {
                    const float4 v = bf4_to_f4(u[t]);
                    acc.x += v.x; acc.y += v.y; acc.z += v.z; acc.w += v.w;
                }
            }
        }
        if (nv) {
            const float d2 = dinv2[n];
            float4 sn;
            if (FIRST) {
                sn.x = -d2 * acc.x; sn.y = -d2 * acc.y;
                sn.z = -d2 * acc.z; sn.w = -d2 * acc.w;
            } else {
                const float4 m2 = bf4_to_f4(*(const ushort4*)(Sm2 + (size_t)n * F + fl * 4));
                sn.x = -2.f * d2 * acc.x - m2.x; sn.y = -2.f * d2 * acc.y - m2.y;
                sn.z = -2.f * d2 * acc.z - m2.z; sn.w = -2.f * d2 * acc.w - m2.w;
            }
            ushort4 o;
            o.x = f_to_bf(sn.x); o.y = f_to_bf(sn.y);
            o.z = f_to_bf(sn.z); o.w = f_to_bf(sn.w);
            *(ushort4*)(Sk + (size_t)n * F + fl * 4) = o;
        }
    }
}

// out = relu(b + rdinv (.) sum_{k=0..5} Sk@Wk)   [x@W0 folded: x = rdinv*S0]
// deg-0 fixup: out = relu(b + x@(W0 - W2 + W4)).
// One WAVE per 16-row tile, all 4 feature tiles per wave (48 MFMAs).
// nt loads on single-use Sstack reads; nt stores on out.
__global__ __launch_bounds__(256, 3)
void mfma_out_kernel(const float* __restrict__ x, const unsigned short* __restrict__ Sstack,
                     const unsigned short* __restrict__ Wfrag, const float* __restrict__ rdinv,
                     const float* __restrict__ dinv2, const float* __restrict__ W,
                     const float* __restrict__ b, float* __restrict__ out, int N, int NF) {
    const int lane = threadIdx.x & 63;
    const int wave = threadIdx.x >> 6;      // row tile within block
    const int quad = lane >> 4;
    const int fl = lane & 15;
    const int tm = (blockIdx.x * 4 + wave) * 16;
    if (tm >= N) return;
    const int ma = tm + fl;
    const int mac = ma < N ? ma : N - 1;

    const unsigned short* sa = Sstack + (size_t)mac * F + quad * 8;

    // preload all 12 A fragments (independent loads in flight, single-use -> nt)
    short8 Afr[12];
#pragma unroll
    for (int s = 0; s < 12; ++s) {
        const int kk = s >> 1, f0 = (s & 1) * 32;
        Afr[s] = __builtin_nontemporal_load((const short8*)(sa + (size_t)kk * NF + f0));
    }

    floatx4 C0 = {0.f, 0.f, 0.f, 0.f};
    floatx4 C1 = {0.f, 0.f, 0.f, 0.f};
    floatx4 C2 = {0.f, 0.f, 0.f, 0.f};
    floatx4 C3 = {0.f, 0.f, 0.f, 0.f};
    const unsigned short* wf = Wfrag + (size_t)lane * 8;
#pragma unroll
    for (int s = 0; s < 12; ++s) {
        const short8 B0 = *(const short8*)(wf + (size_t)(0 * 12 + s) * 64 * 8);
        const short8 B1 = *(const short8*)(wf + (size_t)(1 * 12 + s) * 64 * 8);
        const short8 B2 = *(const short8*)(wf + (size_t)(2 * 12 + s) * 64 * 8);
        const short8 B3 = *(const short8*)(wf + (size_t)(3 * 12 + s) * 64 * 8);
        C0 = __builtin_amdgcn_mfma_f32_16x16x32_bf16(Afr[s], B0, C0, 0, 0, 0);
        C1 = __builtin_amdgcn_mfma_f32_16x16x32_bf16(Afr[s], B1, C1, 0, 0, 0);
        C2 = __builtin_amdgcn_mfma_f32_16x16x32_bf16(Afr[s], B2, C2, 0, 0, 0);
        C3 = __builtin_amdgcn_mfma_f32_16x16x32_bf16(Afr[s], B3, C3, 0, 0, 0);
    }

    const float bl0 = b[0 * 16 + fl];
    const float bl1 = b[1 * 16 + fl];
    const float bl2 = b[2 * 16 + fl];
    const float bl3 = b[3 * 16 + fl];

#pragma unroll
    for (int r = 0; r < 4; ++r) {
        const int m = tm + quad * 4 + r;
        if (m >= N) continue;
        const float rs = rdinv[m];
        const bool z = (dinv2[m] == 0.0f);
        float v0 = rs * C0[r], v1 = rs * C1[r], v2 = rs * C2[r], v3 = rs * C3[r];
        if (z) {  // rare deg-0 rows: out = b + x@(W0 - W2 + W4)
            const float* xr = x + (size_t)m * F;
            float f0 = 0.f, f1 = 0.f, f2 = 0.f, f3 = 0.f;
            for (int f = 0; f < F; ++f) {
                const float xv = xr[f];
                const float* w0 = W + 0 * F * F + f * F;
                const float* w2 = W + 2 * F * F + f * F;
                const float* w4 = W + 4 * F * F + f * F;
                f0 += xv * (w0[0 * 16 + fl] - w2[0 * 16 + fl] + w4[0 * 16 + fl]);
                f1 += xv * (w0[1 * 16 + fl] - w2[1 * 16 + fl] + w4[1 * 16 + fl]);
                f2 += xv * (w0[2 * 16 + fl] - w2[2 * 16 + fl] + w4[2 * 16 + fl]);
                f3 += xv * (w0[3 * 16 + fl] - w2[3 * 16 + fl] + w4[3 * 16 + fl]);
            }
            v0 = f0; v1 = f1; v2 = f2; v3 = f3;
        }
        float* orow = out + (size_t)m * F;
        __builtin_nontemporal_store(fmaxf(v0 + bl0, 0.f), orow + 0 * 16 + fl);
        __builtin_nontemporal_store(fmaxf(v1 + bl1, 0.f), orow + 1 * 16 + fl);
        __builtin_nontemporal_store(fmaxf(v2 + bl2, 0.f), orow + 2 * 16 + fl);
        __builtin_nontemporal_store(fmaxf(v3 + bl3, 0.f), orow + 3 * 16 + fl);
    }
}

extern "C" void kernel_launch(void* const* d_in, const int* in_sizes, int n_in,
                              void* d_out, int out_size, void* d_ws, size_t ws_size,
                              hipStream_t stream) {
    const float* x = (const float*)d_in[0];
    const int* ei = (const int*)d_in[1];
    const float* W = (const float*)d_in[2];
    const float* b = (const float*)d_in[3];

    const int N = in_sizes[0] / F;
    const int E = in_sizes[1] / 2;
    const int NF = N * F;
    const int* row = ei;      // sources j
    const int* col = ei + E;  // targets i

    const int P = (N + 511) >> BSH;           // buckets (<=256 for N<=131072)
    const int G = (E + EPB - 1) / EPB;        // partition blocks
    const int M = P * G;                      // per-chain scan length
    const int M2 = 2 * M;                     // merged scan length

    // workspace allocator (64B-aligned chunks)
    char* p = (char*)d_ws;
    auto alloc = [&](size_t bytes) {
        char* r = p;
        p += (bytes + 63) & ~(size_t)63;
        return r;
    };
    float* dinv   = (float*)alloc((size_t)N * sizeof(float));
    float* dinv2  = (float*)alloc((size_t)N * sizeof(float));
    float* rdinv  = (float*)alloc((size_t)N * sizeof(float));
    int*   rowptr = (int*)alloc((size_t)(N + 1) * sizeof(int));
    int*   bsum   = (int*)alloc(256 * sizeof(int));
    int*   boff   = (int*)alloc(256 * sizeof(int));
    int*   totS   = (int*)alloc(64);
    int*   gc     = (int*)alloc((size_t)M2 * sizeof(int));  // [gcH | gcS]
    int*   go     = (int*)alloc((size_t)M2 * sizeof(int));  // [goH | goS(+E)]
    int*   csr    = (int*)alloc((size_t)E * sizeof(int));
    unsigned short* Sstack = (unsigned short*)alloc((size_t)6 * NF * sizeof(unsigned short));
    unsigned short* Wfrag  = (unsigned short*)alloc((size_t)4 * 12 * 64 * 8 * sizeof(unsigned short));
    // partH (E int, packed) aliases S0 (dead before init_ws0); partS (E int) aliases S1+.
    int* partH = (int*)Sstack;
    int* partS = (int*)(Sstack + (size_t)NF);
    float* out = (float*)d_out;
    (void)ws_size;

    const int B = 256;
    const int nsb = (M2 + SCAN_ELEMS - 1) / SCAN_ELEMS;  // <=256 required
    const int pgrid = (N + 4 * PNPW - 1) / (4 * PNPW);   // 4 waves/block
    const int igrid = WFRAG_BLOCKS + (NF / 4 + B - 1) / B;

    hist2_kernel<<<G, B, 0, stream>>>(row, col, gc, gc + M, P, G, E);
    scan1_kernel<<<nsb, B, 0, stream>>>(gc, bsum, M2);
    scan2_kernel<<<1, B, 0, stream>>>(bsum, boff, totS, nsb);
    scan3_kernel<<<nsb, B, 0, stream>>>(gc, boff, go, M2);
    part2_kernel<<<G, B, 0, stream>>>(row, col, go, go + M, partH, partS, P, G, E);
    bucketCD_kernel<<<2 * P, B, 0, stream>>>(partH, go, partS, go + M, rowptr, csr,
                                             dinv, dinv2, rdinv, P, G, N, E);
    init_ws0_kernel<<<igrid, B, 0, stream>>>(W, Wfrag, dinv, x, Sstack, NF);

    unsigned short* S1 = Sstack + (size_t)1 * NF;
    unsigned short* S2 = Sstack + (size_t)2 * NF;
    unsigned short* S3 = Sstack + (size_t)3 * NF;
    unsigned short* S4 = Sstack + (size_t)4 * NF;
    unsigned short* S5 = Sstack + (size_t)5 * NF;
    prop_g4<1><<<pgrid, B, 0, stream>>>(rowptr, csr, dinv2, Sstack, Sstack, S1, N);
    prop_g4<0><<<pgrid, B, 0, stream>>>(rowptr, csr, dinv2, S1, Sstack, S2, N);
    prop_g4<0><<<pgrid, B, 0, stream>>>(rowptr, csr, dinv2, S2, S1, S3, N);
    prop_g4<0><<<pgrid, B, 0, stream>>>(rowptr, csr, dinv2, S3, S2, S4, N);
    prop_g4<0><<<pgrid, B, 0, stream>>>(rowptr, csr, dinv2, S4, S3, S5, N);
    mfma_out_kernel<<<(N + 63) / 64, 256, 0, stream>>>(x, Sstack, Wfrag, rdinv, dinv2,
                                                       W, b, out, N, NF);
}